// Round 2
// baseline (687.014 us; speedup 1.0000x reference)
//
#include <hip/hip_runtime.h>
#include <hip/hip_bf16.h>
#include <math.h>

// Problem constants (B=16, L=4096, H=1024)
#define BB 16
#define LL 4096
#define HH 1024

// ws layout:
//   [0, 2MB)              : w_e image — bf16, transposed [n][k], per-32-k-step 64KB tiles,
//                           XOR-swizzled so scorek can global_load_lds it linearly
//   [2MB, 2MB+64KB)       : proj_h  (16 x 1024 f32)
//   [+64KB, +320KB)       : scores  (16 x 4096 f32)
//   [+320KB, +576KB)      : weights (16 x 4096 f32)
#define OFF_PH   (2u << 20)
#define OFF_SC   (OFF_PH + 65536u)
#define OFF_WT   (OFF_SC + 262144u)

typedef short s16x8 __attribute__((ext_vector_type(8)));   // 8 bf16 (guide §3 frag type)
typedef float f32x4 __attribute__((ext_vector_type(4)));

__device__ __forceinline__ unsigned short f2bf(float f) {
  unsigned int x = __float_as_uint(f);
  unsigned int r = (x + 0x7FFFu + ((x >> 16) & 1u)) >> 16;  // RNE
  return (unsigned short)r;
}
__device__ __forceinline__ unsigned int pack2(float a, float b) {
  return (unsigned int)f2bf(a) | ((unsigned int)f2bf(b) << 16);
}
__device__ __forceinline__ void glds16(const void* g, void* l) {
  __builtin_amdgcn_global_load_lds((const unsigned int*)g, (unsigned int*)l, 16, 0, 0);
}

// ---------------------------------------------------------------- zero output
__global__ void zerok(float* out) {
  out[blockIdx.x * 1024 + threadIdx.x] = 0.0f;
}

// ---------------------------------------------------------------- proj_h
// ph[b][h] = sum_k rep_h[b][k] * attn_w[k][h] + attn_b[h],  rep_h[k]=hidden[b][k&511]
__global__ void projhk(const float* __restrict__ hidden, const float* __restrict__ attn_w,
                       const float* __restrict__ attn_b, float* __restrict__ ph) {
  const int b = blockIdx.x >> 2;
  const int h = (blockIdx.x & 3) * 256 + threadIdx.x;
  const float* hid = hidden + b * 512;
  float acc = attn_b[h];
#pragma unroll 8
  for (int k = 0; k < 1024; ++k)
    acc += hid[k & 511] * attn_w[k * HH + h];
  ph[b * HH + h] = acc;
}

// ---------------------------------------------------------------- w_e image
// For k-step s (32 k's) the 64KB tile holds bf16 w_e[k][n] at byte
//   (n*64 + (k_local/8)*16 + (k_local%8)*2) ^ ((n&7)<<4)
// i.e. n-major, k-contiguous groups of 8 (one ds_read_b128 = one B-fragment),
// pre-swizzled so linear global_load_lds lands bank-conflict-free for reads.
__global__ void wimgk(const float* __restrict__ attn_w, unsigned char* __restrict__ img) {
  const int step = blockIdx.x >> 4;   // 0..31
  const int nt   = blockIdx.x & 15;   // 0..15
  const int t    = threadIdx.x;       // 256
  const int nl = t & 63, kg = t >> 6; // kg 0..3
  const int n = nt * 64 + nl;
  unsigned short u[8];
#pragma unroll
  for (int j = 0; j < 8; ++j) {
    float f = attn_w[(size_t)(1024 + step * 32 + kg * 8 + j) * HH + n];
    u[j] = f2bf(f);
  }
  uint4 p;
  p.x = (unsigned int)u[0] | ((unsigned int)u[1] << 16);
  p.y = (unsigned int)u[2] | ((unsigned int)u[3] << 16);
  p.z = (unsigned int)u[4] | ((unsigned int)u[5] << 16);
  p.w = (unsigned int)u[6] | ((unsigned int)u[7] << 16);
  unsigned int off = ((unsigned int)(n * 64 + kg * 16)) ^ ((unsigned int)(n & 7) << 4);
  *(uint4*)(img + (size_t)step * 65536 + off) = p;
}

// ---------------------------------------------------------------- scores
// One block = 64 consecutive rows of (b,l), all N=1024 accumulated in registers.
// 8 waves, wave w owns n in [w*128, w*128+128): acc[4 mf][8 nf] f32x4 = 128 VGPR.
// K-loop: 32 steps of K=32. w tile (64KB) double-buffered via global_load_lds;
// enc chunk (64 rows x 64 k, bf16, 8KB) reg-staged+converted, double-buffered.
__global__ __launch_bounds__(512, 2) void scorek(
    const float* __restrict__ enc, const unsigned char* __restrict__ wimg,
    const float* __restrict__ ph, const float* __restrict__ vw,
    float* __restrict__ scores) {
  __shared__ __align__(16) unsigned char wlds[2][65536];
  __shared__ __align__(16) unsigned char elds[2][8192];
  __shared__ float red[64];

  const int t = threadIdx.x;
  const int lane = t & 63;
  const int wave = t >> 6;
  const int kg = lane >> 4;   // 0..3  -> k-subgroup of the MFMA fragment
  const int lr = lane & 15;
  const int g0 = blockIdx.x << 6;   // global row (b*L + l)
  const int bidx = g0 >> 12;

  if (t < 64) red[t] = 0.0f;

  // enc staging role: thread -> (row em, k-group ek): 64 rows x 8 groups of 8 floats
  const int em = t >> 3;
  const int ek = t & 7;
  const float* encbase = enc + (size_t)(g0 + em) * HH + ek * 8;
  const int ewoff = ((em * 128 + ek * 16) ^ ((em & 7) << 4));

  // fragment LDS read offsets (XOR swizzle; low-3 row/col bits == lr&7)
  const int exr = (lr & 7) << 4;
  int aoff[4];
#pragma unroll
  for (int mf = 0; mf < 4; ++mf)
    aoff[mf] = (((mf * 16 + lr) * 128 + kg * 16) ^ exr);  // odd k-half: ^64
  int boff[8];
#pragma unroll
  for (int nf = 0; nf < 8; ++nf)
    boff[nf] = (((wave * 128 + nf * 16 + lr) * 64 + kg * 16) ^ exr);

  f32x4 acc[4][8];
#pragma unroll
  for (int mf = 0; mf < 4; ++mf)
#pragma unroll
    for (int nf = 0; nf < 8; ++nf)
      acc[mf][nf] = (f32x4){0.f, 0.f, 0.f, 0.f};

  float4 er0, er1;

  // prologue: stage w step0 (async) + enc chunk0 (regs -> cvt -> LDS)
  {
#pragma unroll
    for (int i = 0; i < 8; ++i)
      glds16(wimg + t * 16 + i * 8192, &wlds[0][t * 16 + i * 8192]);
    er0 = *(const float4*)(encbase);
    er1 = *(const float4*)(encbase + 4);
    uint4 p;
    p.x = pack2(er0.x, er0.y); p.y = pack2(er0.z, er0.w);
    p.z = pack2(er1.x, er1.y); p.w = pack2(er1.z, er1.w);
    *(uint4*)(&elds[0][ewoff]) = p;
    __syncthreads();  // drains vmcnt (glds) + lgkm
  }

#pragma unroll 1
  for (int s2 = 0; s2 < 16; ++s2) {
    // ---- even step s=2*s2: compute from wlds[0], elds[s2&1] (k-half 0)
    {
      const unsigned char* src = wimg + (size_t)(2 * s2 + 1) * 65536;
#pragma unroll
      for (int i = 0; i < 8; ++i)
        glds16(src + t * 16 + i * 8192, &wlds[1][t * 16 + i * 8192]);
      if (s2 < 15) {  // prefetch enc chunk s2+1 into regs (HBM latency hidden under MFMAs)
        er0 = *(const float4*)(encbase + (s2 + 1) * 64);
        er1 = *(const float4*)(encbase + (s2 + 1) * 64 + 4);
      }
      const unsigned char* wb = wlds[0];
      const unsigned char* eb = elds[s2 & 1];
      s16x8 a[4];
#pragma unroll
      for (int mf = 0; mf < 4; ++mf)
        a[mf] = *(const s16x8*)(eb + aoff[mf]);
#pragma unroll
      for (int nf = 0; nf < 8; ++nf) {
        s16x8 b = *(const s16x8*)(wb + boff[nf]);
#pragma unroll
        for (int mf = 0; mf < 4; ++mf)
          acc[mf][nf] = __builtin_amdgcn_mfma_f32_16x16x32_bf16(a[mf], b, acc[mf][nf], 0, 0, 0);
      }
      __syncthreads();
    }
    // ---- odd step s=2*s2+1: compute from wlds[1], elds[s2&1] (k-half 1)
    {
      if (s2 < 15) {
        uint4 p;  // write enc chunk s2+1 (its readers finished 2 barriers ago)
        p.x = pack2(er0.x, er0.y); p.y = pack2(er0.z, er0.w);
        p.z = pack2(er1.x, er1.y); p.w = pack2(er1.z, er1.w);
        *(uint4*)(&elds[(s2 + 1) & 1][ewoff]) = p;
        const unsigned char* src = wimg + (size_t)(2 * s2 + 2) * 65536;
#pragma unroll
        for (int i = 0; i < 8; ++i)
          glds16(src + t * 16 + i * 8192, &wlds[0][t * 16 + i * 8192]);
      }
      const unsigned char* wb = wlds[1];
      const unsigned char* eb = elds[s2 & 1];
      s16x8 a[4];
#pragma unroll
      for (int mf = 0; mf < 4; ++mf)
        a[mf] = *(const s16x8*)(eb + (aoff[mf] ^ 64));  // bit6 clear in base -> XOR ok
#pragma unroll
      for (int nf = 0; nf < 8; ++nf) {
        s16x8 b = *(const s16x8*)(wb + boff[nf]);
#pragma unroll
        for (int mf = 0; mf < 4; ++mf)
          acc[mf][nf] = __builtin_amdgcn_mfma_f32_16x16x32_bf16(a[mf], b, acc[mf][nf], 0, 0, 0);
      }
      __syncthreads();
    }
  }

  // ---- epilogue: score[row] = sum_n vw[n] * tanh(acc + ph[b][n])
  float phv[8], vwv[8];
#pragma unroll
  for (int nf = 0; nf < 8; ++nf) {
    int col = wave * 128 + nf * 16 + lr;
    phv[nf] = ph[bidx * HH + col];
    vwv[nf] = vw[col];
  }
  float part[4][4];
#pragma unroll
  for (int mf = 0; mf < 4; ++mf) {
#pragma unroll
    for (int i = 0; i < 4; ++i) {
      float s = 0.f;
#pragma unroll
      for (int nf = 0; nf < 8; ++nf)
        s += vwv[nf] * tanhf(acc[mf][nf][i] + phv[nf]);
      part[mf][i] = s;
    }
  }
  // reduce over the 16 col-lanes (D layout: col = lane&15, row = kg*4+i)
#pragma unroll
  for (int mask = 1; mask < 16; mask <<= 1) {
#pragma unroll
    for (int mf = 0; mf < 4; ++mf)
#pragma unroll
      for (int i = 0; i < 4; ++i)
        part[mf][i] += __shfl_xor(part[mf][i], mask, 64);
  }
  if (lr == 0) {
#pragma unroll
    for (int mf = 0; mf < 4; ++mf)
#pragma unroll
      for (int i = 0; i < 4; ++i)
        atomicAdd(&red[mf * 16 + kg * 4 + i], part[mf][i]);
  }
  __syncthreads();
  if (t < 64) scores[g0 + t] = red[t];
}

// ---------------------------------------------------------------- softmax over L
__global__ void smaxk(const float* __restrict__ sc, float* __restrict__ wt) {
  const int b = blockIdx.x, t = threadIdx.x;  // 256 threads, 16 scores each
  const float* s = sc + b * LL;
  float v[16];
#pragma unroll
  for (int i = 0; i < 4; ++i) {
    float4 f = *(const float4*)(s + t * 16 + i * 4);
    v[i * 4 + 0] = f.x; v[i * 4 + 1] = f.y; v[i * 4 + 2] = f.z; v[i * 4 + 3] = f.w;
  }
  float m = -1e30f;
#pragma unroll
  for (int i = 0; i < 16; ++i) m = fmaxf(m, v[i]);
#pragma unroll
  for (int off = 1; off < 64; off <<= 1) m = fmaxf(m, __shfl_xor(m, off, 64));
  __shared__ float wm[4], wsm[4];
  const int wv = t >> 6, ln = t & 63;
  if (ln == 0) wm[wv] = m;
  __syncthreads();
  m = fmaxf(fmaxf(wm[0], wm[1]), fmaxf(wm[2], wm[3]));
  float sum = 0.f;
#pragma unroll
  for (int i = 0; i < 16; ++i) { v[i] = expf(v[i] - m); sum += v[i]; }
#pragma unroll
  for (int off = 1; off < 64; off <<= 1) sum += __shfl_xor(sum, off, 64);
  if (ln == 0) wsm[wv] = sum;
  __syncthreads();
  sum = wsm[0] + wsm[1] + wsm[2] + wsm[3];
  const float inv = 1.0f / sum;
#pragma unroll
  for (int i = 0; i < 4; ++i) {
    float4 f;
    f.x = v[i * 4 + 0] * inv; f.y = v[i * 4 + 1] * inv;
    f.z = v[i * 4 + 2] * inv; f.w = v[i * 4 + 3] * inv;
    *(float4*)(wt + b * LL + t * 16 + i * 4) = f;
  }
}

// ---------------------------------------------------------------- context
// context[b][h] = sum_l wt[b][l] * enc[b][l][h];  1024 blocks = 16 b x 64 l-chunks
__global__ void ctxk(const float* __restrict__ enc, const float* __restrict__ wt,
                     float* __restrict__ out) {
  const int bid = blockIdx.x;
  const int b = bid >> 6;
  const int l0 = (bid & 63) * 64;
  const int t = threadIdx.x;  // 256
  __shared__ float wl[64];
  if (t < 64) wl[t] = wt[b * LL + l0 + t];
  __syncthreads();
  const float* base = enc + (size_t)(b * LL + l0) * HH + t * 4;
  float ax = 0.f, ay = 0.f, az = 0.f, aw = 0.f;
#pragma unroll 4
  for (int l = 0; l < 64; ++l) {
    float4 e = *(const float4*)(base + (size_t)l * HH);
    float w = wl[l];
    ax += w * e.x; ay += w * e.y; az += w * e.z; aw += w * e.w;
  }
  float* o = out + b * HH + t * 4;
  atomicAdd(o + 0, ax); atomicAdd(o + 1, ay);
  atomicAdd(o + 2, az); atomicAdd(o + 3, aw);
}

// ---------------------------------------------------------------- launch
extern "C" void kernel_launch(void* const* d_in, const int* in_sizes, int n_in,
                              void* d_out, int out_size, void* d_ws, size_t ws_size,
                              hipStream_t stream) {
  (void)in_sizes; (void)n_in; (void)out_size; (void)ws_size;
  const float* hidden = (const float*)d_in[0];
  const float* enc    = (const float*)d_in[1];
  const float* attn_w = (const float*)d_in[2];
  const float* attn_b = (const float*)d_in[3];
  const float* v_w    = (const float*)d_in[4];
  float* out = (float*)d_out;
  unsigned char* ws = (unsigned char*)d_ws;

  unsigned char* wimg = ws;
  float* ph     = (float*)(ws + OFF_PH);
  float* scores = (float*)(ws + OFF_SC);
  float* wts    = (float*)(ws + OFF_WT);

  zerok<<<dim3(16), dim3(1024), 0, stream>>>(out);
  projhk<<<dim3(64), dim3(256), 0, stream>>>(hidden, attn_w, attn_b, ph);
  wimgk<<<dim3(512), dim3(256), 0, stream>>>(attn_w, wimg);
  scorek<<<dim3(1024), dim3(512), 0, stream>>>(enc, wimg, ph, v_w, scores);
  smaxk<<<dim3(16), dim3(256), 0, stream>>>(scores, wts);
  ctxk<<<dim3(1024), dim3(256), 0, stream>>>(enc, wts, out);
}

// Round 4
// 623.568 us; speedup vs baseline: 1.1017x; 1.1017x over previous
//
#include <hip/hip_runtime.h>
#include <hip/hip_bf16.h>
#include <math.h>

// Problem constants (B=16, L=4096, H=1024)
#define BB 16
#define LL 4096
#define HH 1024

// ws layout:
//   [0, 2MB)   : w_e image (scorek phase) THEN ctx partials (ctx phase, 512x1024 f32 = 2MB)
//   [2MB, +64KB)   : proj_h  (16 x 1024 f32)
//   [+64KB, +320KB): scores  (16 x 4096 f32)
//   [+320KB,+576KB): weights (16 x 4096 f32)
#define OFF_PH   (2u << 20)
#define OFF_SC   (OFF_PH + 65536u)
#define OFF_WT   (OFF_SC + 262144u)

typedef short s16x8 __attribute__((ext_vector_type(8)));   // 8 bf16 (guide §3 frag type)
typedef float f32x4 __attribute__((ext_vector_type(4)));

__device__ __forceinline__ unsigned short f2bf(float f) {
  unsigned int x = __float_as_uint(f);
  unsigned int r = (x + 0x7FFFu + ((x >> 16) & 1u)) >> 16;  // RNE
  return (unsigned short)r;
}
__device__ __forceinline__ void glds16(const void* g, void* l) {
  __builtin_amdgcn_global_load_lds((const unsigned int*)g, (unsigned int*)l, 16, 0, 0);
}
// 8 f32 -> 8 bf16 (compiler emits v_cvt_pk_bf16_f32; m240: don't hand-write asm)
__device__ __forceinline__ uint4 pack8(float4 u, float4 v) {
  union { uint4 q; __bf16 h[8]; } r;
  r.h[0] = (__bf16)u.x; r.h[1] = (__bf16)u.y; r.h[2] = (__bf16)u.z; r.h[3] = (__bf16)u.w;
  r.h[4] = (__bf16)v.x; r.h[5] = (__bf16)v.y; r.h[6] = (__bf16)v.z; r.h[7] = (__bf16)v.w;
  return r.q;
}
// tanh(x) = 1 - 2/(e^{2x}+1); saturates correctly at +/-inf; err ~1e-6 << bf16 noise
__device__ __forceinline__ float fast_tanh(float x) {
  float e = __expf(2.0f * x);
  return 1.0f - 2.0f * __builtin_amdgcn_rcpf(e + 1.0f);
}

// ---------------------------------------------------------------- proj_h
__global__ void projhk(const float* __restrict__ hidden, const float* __restrict__ attn_w,
                       const float* __restrict__ attn_b, float* __restrict__ ph) {
  const int b = blockIdx.x >> 2;
  const int h = (blockIdx.x & 3) * 256 + threadIdx.x;
  const float* hid = hidden + b * 512;
  float acc = attn_b[h];
#pragma unroll 8
  for (int k = 0; k < 1024; ++k)
    acc += hid[k & 511] * attn_w[k * HH + h];
  ph[b * HH + h] = acc;
}

// ---------------------------------------------------------------- w_e image
// k-step s (32 k's): 64KB tile, bf16 w_e[k][n] at byte
//   (n*64 + (k_local/8)*16 + (k_local%8)*2) ^ ((n&7)<<4)
__global__ void wimgk(const float* __restrict__ attn_w, unsigned char* __restrict__ img) {
  const int step = blockIdx.x >> 4;   // 0..31
  const int nt   = blockIdx.x & 15;   // 0..15
  const int t    = threadIdx.x;       // 256
  const int nl = t & 63, kg = t >> 6; // kg 0..3
  const int n = nt * 64 + nl;
  unsigned short u[8];
#pragma unroll
  for (int j = 0; j < 8; ++j) {
    float f = attn_w[(size_t)(1024 + step * 32 + kg * 8 + j) * HH + n];
    u[j] = f2bf(f);
  }
  uint4 p;
  p.x = (unsigned int)u[0] | ((unsigned int)u[1] << 16);
  p.y = (unsigned int)u[2] | ((unsigned int)u[3] << 16);
  p.z = (unsigned int)u[4] | ((unsigned int)u[5] << 16);
  p.w = (unsigned int)u[6] | ((unsigned int)u[7] << 16);
  unsigned int off = ((unsigned int)(n * 64 + kg * 16)) ^ ((unsigned int)(n & 7) << 4);
  *(uint4*)(img + (size_t)step * 65536 + off) = p;
}

// ---------------------------------------------------------------- scores
// Counted-vmcnt pipeline (T3-lite/T4): raw s_barrier, constant vmcnt(10).
// Per-step ledger (per wave: 8 w-glds + 2 enc loads every other step):
//   s even: issue w@s+1(8), issue enc chunk s/2+2(2) -> outstanding 20 -> vmcnt(10)
//           drains [enc chunk s/2, w@s]; leaves [w@s+1, enc s/2+2].
//   s odd : issue w@s+1(8) -> outstanding 18 -> vmcnt(10) drains w@s.
// Tail steps issue wrapped dummy loads so counts stay uniform.
__global__ __launch_bounds__(512, 2) void scorek(
    const float* __restrict__ enc, const unsigned char* __restrict__ wimg,
    const float* __restrict__ ph, const float* __restrict__ vw,
    float* __restrict__ scores) {
  __shared__ __align__(16) unsigned char wlds[2][65536];
  __shared__ __align__(16) unsigned char elds[2][8192];
  __shared__ float red[64];

  const int t = threadIdx.x;
  const int lane = t & 63;
  const int wave = t >> 6;
  const int kg = lane >> 4;
  const int lr = lane & 15;
  const int g0 = blockIdx.x << 6;   // global row (b*L + l)
  const int bidx = g0 >> 12;

  if (t < 64) red[t] = 0.0f;

  // enc staging role: thread -> (row em, k-group ek)
  const int em = t >> 3;
  const int ek = t & 7;
  const float* encbase = enc + (size_t)(g0 + em) * HH + ek * 8;
  const int ewoff = ((em * 128 + ek * 16) ^ ((em & 7) << 4));

  const int exr = (lr & 7) << 4;
  int aoff[4];
#pragma unroll
  for (int mf = 0; mf < 4; ++mf)
    aoff[mf] = (((mf * 16 + lr) * 128 + kg * 16) ^ exr);
  int boff[8];
#pragma unroll
  for (int nf = 0; nf < 8; ++nf)
    boff[nf] = (((wave * 128 + nf * 16 + lr) * 64 + kg * 16) ^ exr);

  f32x4 acc[4][8];
#pragma unroll
  for (int mf = 0; mf < 4; ++mf)
#pragma unroll
    for (int nf = 0; nf < 8; ++nf)
      acc[mf][nf] = (f32x4){0.f, 0.f, 0.f, 0.f};

  float4 ea0, ea1, eb0, eb1;   // two enc reg sets by chunk parity (static names: rule #20)

  // ---- prologue: w@0 -> wlds[0]; chunk0 -> setA; chunk1 -> setB; write chunk0 -> elds[0]
  {
#pragma unroll
    for (int i = 0; i < 8; ++i)
      glds16(wimg + t * 16 + i * 8192, &wlds[0][t * 16 + i * 8192]);
    ea0 = *(const float4*)(encbase);
    ea1 = *(const float4*)(encbase + 4);
    eb0 = *(const float4*)(encbase + 64);
    eb1 = *(const float4*)(encbase + 64 + 4);
    asm volatile("s_waitcnt vmcnt(2)" ::: "memory");   // w@0 + chunk0 in; chunk1 in flight
    __builtin_amdgcn_sched_barrier(0);
    *(uint4*)(&elds[0][ewoff]) = pack8(ea0, ea1);
    asm volatile("s_waitcnt lgkmcnt(0)" ::: "memory");
    __builtin_amdgcn_s_barrier();
  }

#define ISSUE_W(dstbuf) do { \
    const unsigned char* wsrc_ = wimg + ((size_t)((s + 1) & 31) << 16); \
    _Pragma("unroll") \
    for (int i = 0; i < 8; ++i) \
      glds16(wsrc_ + t * 16 + i * 8192, &wlds[dstbuf][t * 16 + i * 8192]); \
  } while (0)

#define LOAD_ENC(r0, r1) do { \
    int ck_ = ((s >> 1) + 2) & 15; \
    r0 = *(const float4*)(encbase + ck_ * 64); \
    r1 = *(const float4*)(encbase + ck_ * 64 + 4); \
  } while (0)

#define WRITE_ENC(dstbuf, r0, r1) do { \
    *(uint4*)(&elds[dstbuf][ewoff]) = pack8(r0, r1); \
  } while (0)

#define COMPUTE(wbuf, ebuf, kh) do { \
    asm volatile("s_waitcnt vmcnt(10)" ::: "memory"); \
    __builtin_amdgcn_sched_barrier(0); \
    const unsigned char* wb_ = wlds[wbuf]; \
    const unsigned char* eb_ = elds[ebuf]; \
    s16x8 a_[4]; \
    _Pragma("unroll") \
    for (int mf = 0; mf < 4; ++mf) a_[mf] = *(const s16x8*)(eb_ + (aoff[mf] ^ (kh))); \
    __builtin_amdgcn_s_setprio(1); \
    _Pragma("unroll") \
    for (int nf = 0; nf < 8; ++nf) { \
      s16x8 b_ = *(const s16x8*)(wb_ + boff[nf]); \
      _Pragma("unroll") \
      for (int mf = 0; mf < 4; ++mf) \
        acc[mf][nf] = __builtin_amdgcn_mfma_f32_16x16x32_bf16(a_[mf], b_, acc[mf][nf], 0, 0, 0); \
    } \
    __builtin_amdgcn_s_setprio(0); \
    asm volatile("s_waitcnt lgkmcnt(0)" ::: "memory"); \
    __builtin_amdgcn_s_barrier(); \
  } while (0)

#pragma unroll 1
  for (int s4 = 0; s4 < 8; ++s4) {
    int s;
    s = s4 * 4 + 0; ISSUE_W(1); LOAD_ENC(ea0, ea1);  COMPUTE(0, 0, 0);
    s = s4 * 4 + 1; ISSUE_W(0); WRITE_ENC(1, eb0, eb1); COMPUTE(1, 0, 64);
    s = s4 * 4 + 2; ISSUE_W(1); LOAD_ENC(eb0, eb1);  COMPUTE(0, 1, 0);
    s = s4 * 4 + 3; ISSUE_W(0); WRITE_ENC(0, ea0, ea1); COMPUTE(1, 1, 64);
  }
#undef ISSUE_W
#undef LOAD_ENC
#undef WRITE_ENC
#undef COMPUTE

  // ---- epilogue: score[row] = sum_n vw[n] * tanh(acc + ph[b][n])
  float phv[8], vwv[8];
#pragma unroll
  for (int nf = 0; nf < 8; ++nf) {
    int col = wave * 128 + nf * 16 + lr;
    phv[nf] = ph[bidx * HH + col];
    vwv[nf] = vw[col];
  }
  float part[4][4];
#pragma unroll
  for (int mf = 0; mf < 4; ++mf) {
#pragma unroll
    for (int i = 0; i < 4; ++i) {
      float s = 0.f;
#pragma unroll
      for (int nf = 0; nf < 8; ++nf)
        s += vwv[nf] * fast_tanh(acc[mf][nf][i] + phv[nf]);
      part[mf][i] = s;
    }
  }
#pragma unroll
  for (int mask = 1; mask < 16; mask <<= 1) {
#pragma unroll
    for (int mf = 0; mf < 4; ++mf)
#pragma unroll
      for (int i = 0; i < 4; ++i)
        part[mf][i] += __shfl_xor(part[mf][i], mask, 64);
  }
  if (lr == 0) {
#pragma unroll
    for (int mf = 0; mf < 4; ++mf)
#pragma unroll
      for (int i = 0; i < 4; ++i)
        atomicAdd(&red[mf * 16 + kg * 4 + i], part[mf][i]);
  }
  __syncthreads();
  if (t < 64) scores[g0 + t] = red[t];
}

// ---------------------------------------------------------------- softmax over L
__global__ void smaxk(const float* __restrict__ sc, float* __restrict__ wt) {
  const int b = blockIdx.x, t = threadIdx.x;
  const float* s = sc + b * LL;
  float v[16];
#pragma unroll
  for (int i = 0; i < 4; ++i) {
    float4 f = *(const float4*)(s + t * 16 + i * 4);
    v[i * 4 + 0] = f.x; v[i * 4 + 1] = f.y; v[i * 4 + 2] = f.z; v[i * 4 + 3] = f.w;
  }
  float m = -1e30f;
#pragma unroll
  for (int i = 0; i < 16; ++i) m = fmaxf(m, v[i]);
#pragma unroll
  for (int off = 1; off < 64; off <<= 1) m = fmaxf(m, __shfl_xor(m, off, 64));
  __shared__ float wm[4], wsm[4];
  const int wv = t >> 6, ln = t & 63;
  if (ln == 0) wm[wv] = m;
  __syncthreads();
  m = fmaxf(fmaxf(wm[0], wm[1]), fmaxf(wm[2], wm[3]));
  float sum = 0.f;
#pragma unroll
  for (int i = 0; i < 16; ++i) { v[i] = expf(v[i] - m); sum += v[i]; }
#pragma unroll
  for (int off = 1; off < 64; off <<= 1) sum += __shfl_xor(sum, off, 64);
  if (ln == 0) wsm[wv] = sum;
  __syncthreads();
  sum = wsm[0] + wsm[1] + wsm[2] + wsm[3];
  const float inv = 1.0f / sum;
#pragma unroll
  for (int i = 0; i < 4; ++i) {
    float4 f;
    f.x = v[i * 4 + 0] * inv; f.y = v[i * 4 + 1] * inv;
    f.z = v[i * 4 + 2] * inv; f.w = v[i * 4 + 3] * inv;
    *(float4*)(wt + b * LL + t * 16 + i * 4) = f;
  }
}

// ---------------------------------------------------------------- context, stage 1
// part[b*32+lc][h] = sum over 128 l's of wt*enc. 512 blocks, no atomics.
__global__ void ctxk1(const float* __restrict__ enc, const float* __restrict__ wt,
                      float* __restrict__ part) {
  const int b = blockIdx.x >> 5;
  const int lc = blockIdx.x & 31;
  const int t = threadIdx.x;  // 256
  __shared__ float wl[128];
  if (t < 128) wl[t] = wt[b * LL + lc * 128 + t];
  __syncthreads();
  const float* base = enc + ((size_t)(b * LL + lc * 128)) * HH + t * 4;
  float ax = 0.f, ay = 0.f, az = 0.f, aw = 0.f;
#pragma unroll 8
  for (int l = 0; l < 128; ++l) {
    float4 e = *(const float4*)(base + (size_t)l * HH);
    float w = wl[l];
    ax += w * e.x; ay += w * e.y; az += w * e.z; aw += w * e.w;
  }
  float4 r; r.x = ax; r.y = ay; r.z = az; r.w = aw;
  *(float4*)(part + (size_t)blockIdx.x * HH + t * 4) = r;
}

// ---------------------------------------------------------------- context, stage 2
__global__ void ctxk2(const float* __restrict__ part, float* __restrict__ out) {
  const int b = blockIdx.x, t = threadIdx.x;  // 16 blocks x 256 threads
  float ax = 0.f, ay = 0.f, az = 0.f, aw = 0.f;
#pragma unroll
  for (int j = 0; j < 32; ++j) {
    float4 p = *(const float4*)(part + (size_t)(b * 32 + j) * HH + t * 4);
    ax += p.x; ay += p.y; az += p.z; aw += p.w;
  }
  float4 r; r.x = ax; r.y = ay; r.z = az; r.w = aw;
  *(float4*)(out + b * HH + t * 4) = r;
}

// ---------------------------------------------------------------- launch
extern "C" void kernel_launch(void* const* d_in, const int* in_sizes, int n_in,
                              void* d_out, int out_size, void* d_ws, size_t ws_size,
                              hipStream_t stream) {
  (void)in_sizes; (void)n_in; (void)out_size; (void)ws_size;
  const float* hidden = (const float*)d_in[0];
  const float* enc    = (const float*)d_in[1];
  const float* attn_w = (const float*)d_in[2];
  const float* attn_b = (const float*)d_in[3];
  const float* v_w    = (const float*)d_in[4];
  float* out = (float*)d_out;
  unsigned char* ws = (unsigned char*)d_ws;

  unsigned char* wimg = ws;                 // 2MB, live during scorek
  float* cpart  = (float*)ws;               // same 2MB, live during ctx phase
  float* ph     = (float*)(ws + OFF_PH);
  float* scores = (float*)(ws + OFF_SC);
  float* wts    = (float*)(ws + OFF_WT);

  projhk<<<dim3(64), dim3(256), 0, stream>>>(hidden, attn_w, attn_b, ph);
  wimgk<<<dim3(512), dim3(256), 0, stream>>>(attn_w, wimg);
  scorek<<<dim3(1024), dim3(512), 0, stream>>>(enc, wimg, ph, v_w, scores);
  smaxk<<<dim3(16), dim3(256), 0, stream>>>(scores, wts);
  ctxk1<<<dim3(512), dim3(256), 0, stream>>>(enc, wts, cpart);
  ctxk2<<<dim3(16), dim3(256), 0, stream>>>(cpart, out);
}